// Round 4
// baseline (100.359 us; speedup 1.0000x reference)
//
#include <hip/hip_runtime.h>

#define GS   7
#define CCH  490
#define HH   128
#define WW   128
#define LDW  132        // padded LDS row stride: conflict-free b128 rows, free b32 cols
#define NB   2
#define NCH  (NB * CCH) // 980 channels total
#define NBLK 512        // persistent blocks, 2 per CU

__global__ __launch_bounds__(512, 4) void psroi_fused(
    const float* __restrict__ rois,
    const float* __restrict__ feat,
    const int*   __restrict__ stride_p,
    float*       __restrict__ out)
{
#pragma clang fp contract(off)
    __shared__ float S[HH * LDW];   // 67,584 B -> 2 blocks/CU

    const int tid = threadIdx.x;
    const int col = tid & 127;      // phase-A mapping
    const int seg = tid >> 7;       // 0..3
    const int r0  = seg * 32;
    const int row = tid >> 2;       // phase-B mapping
    const int ws_ = tid & 3;

    // ---- Hoisted per-RoI geometry (channel-independent), thread n = roi n ----
    const float ss  = 1.0f / (float)(*stride_p);
    const float b_f = rois[tid * 5 + 0];
    const int   bi  = (int)b_f;
    const float x1  = rois[tid * 5 + 1];
    const float y1  = rois[tid * 5 + 2];
    const float x2  = rois[tid * 5 + 3];
    const float y2  = rois[tid * 5 + 4];
    // exact reference op order, fp32, no contraction
    float rsw = rintf(x1) * ss;
    float rsh = rintf(y1) * ss;
    float rew = (rintf(x2) + 1.0f) * ss;
    float reh = (rintf(y2) + 1.0f) * ss;
    float rwm = (rew - rsw) * 1.3f;
    float rhm = (reh - rsh) * 1.3f;
    const float swm = (rsw + rew) * 0.5f - rwm * 0.5f;
    const float shm = (rsh + reh) * 0.5f - rhm * 0.5f;
    rwm = fmaxf(rwm, 0.1f);
    rhm = fmaxf(rhm, 0.1f);
    const float bin_h = rhm / 7.0f;
    const float bin_w = rwm / 7.0f;
    const float dh = bin_h * 0.25f;
    const float dw = bin_w * 0.25f;

    // ---- Preload first channel into registers ----
    int ch = blockIdx.x;
    float v[32];
    {
        const float* __restrict__ fp = feat + (size_t)ch * (HH * WW) + r0 * WW + col;
        #pragma unroll
        for (int i = 0; i < 32; ++i)    // coalesced 256B wave-loads
            v[i] = fp[i * WW];
    }

    while (ch < NCH) {
        const int nxt = ch + NBLK;

        // ---- Prefetch next channel (hidden behind this channel's scan/pool) ----
        float p[32];
        if (nxt < NCH) {
            const float* __restrict__ fp = feat + (size_t)nxt * (HH * WW) + r0 * WW + col;
            #pragma unroll
            for (int i = 0; i < 32; ++i)
                p[i] = fp[i * WW];
        }

        // ---- Phase A: cumsum over H (reference inner axis) ----
        #pragma unroll
        for (int i = 1; i < 32; ++i)    // serial register scan
            v[i] += v[i - 1];

        S[seg * LDW + col] = v[31];     // seg-total exchange
        __syncthreads();
        float offA = 0.0f;              // seg uniform per wave
        if (seg > 0) offA += S[0 * LDW + col];
        if (seg > 1) offA += S[1 * LDW + col];
        if (seg > 2) offA += S[2 * LDW + col];
        __syncthreads();

        {
            float* sp = &S[r0 * LDW + col];
            #pragma unroll
            for (int i = 0; i < 32; ++i)    // imm-offset b32 writes, 2-way banks (free)
                sp[i * LDW] = v[i] + offA;
        }
        __syncthreads();

        // ---- Phase B: cumsum over W; quads share a row ----
        {
            float* rp = &S[row * LDW + ws_ * 32];
            float u[32];
            #pragma unroll
            for (int i = 0; i < 8; ++i) {   // 8x ds_read_b128, conflict-free
                const float4 q = *(const float4*)&rp[i * 4];
                u[4 * i + 0] = q.x; u[4 * i + 1] = q.y;
                u[4 * i + 2] = q.z; u[4 * i + 3] = q.w;
            }
            #pragma unroll
            for (int i = 1; i < 32; ++i)
                u[i] += u[i - 1];

            const float tot = u[31];        // cross-seg fixup within quad
            const float t1 = __shfl_up(tot, 1, 64);
            const float t2 = __shfl_up(tot, 2, 64);
            const float t3 = __shfl_up(tot, 3, 64);
            float offB = 0.0f;
            if (ws_ > 0) offB += t1;
            if (ws_ > 1) offB += t2;
            if (ws_ > 2) offB += t3;

            #pragma unroll
            for (int i = 0; i < 8; ++i) {   // 8x ds_write_b128 in place
                float4 q;
                q.x = u[4 * i + 0] + offB; q.y = u[4 * i + 1] + offB;
                q.z = u[4 * i + 2] + offB; q.w = u[4 * i + 3] + offB;
                *(float4*)&rp[i * 4] = q;
            }
        }
        __syncthreads();

        // ---- Phase 3: pooling — thread n = roi n for this channel ----
        {
            const int b = ch / CCH;
            const int c = ch - b * CCH;
            if (bi == b) {
                const int d   = c / (GS * GS);
                const int rem = c - d * (GS * GS);
                const int pi  = rem / GS;
                const int pj  = rem - pi * GS;
                const float gi = (float)pi;
                const float gj = (float)pj;

                const int hs  = (int)fminf(fmaxf(floorf(shm + gi * bin_h - dh),          0.0f), 128.0f);
                const int he  = (int)fminf(fmaxf(ceilf (shm + (gi + 1.0f) * bin_h + dh), 0.0f), 128.0f);
                const int ws2 = (int)fminf(fmaxf(floorf(swm + gj * bin_w - dw),          0.0f), 128.0f);
                const int we  = (int)fminf(fmaxf(ceilf (swm + (gj + 1.0f) * bin_w + dw), 0.0f), 128.0f);

                const int area = (he - hs) * (we - ws2);
                const float A  = (he > 0 && we  > 0) ? S[(he - 1) * LDW + (we  - 1)] : 0.0f;
                const float Bv = (hs > 0 && we  > 0) ? S[(hs - 1) * LDW + (we  - 1)] : 0.0f;
                const float Cv = (he > 0 && ws2 > 0) ? S[(he - 1) * LDW + (ws2 - 1)] : 0.0f;
                const float Dv = (hs > 0 && ws2 > 0) ? S[(hs - 1) * LDW + (ws2 - 1)] : 0.0f;
                const float total = ((A - Bv) - Cv) + Dv;   // reference order
                out[(size_t)tid * CCH + c] = (area > 0) ? (total / (float)area) : 0.0f;
            }
        }
        __syncthreads();   // S reused by next iteration's phase A

        #pragma unroll
        for (int i = 0; i < 32; ++i)
            v[i] = p[i];
        ch = nxt;
    }
}

extern "C" void kernel_launch(void* const* d_in, const int* in_sizes, int n_in,
                              void* d_out, int out_size, void* d_ws, size_t ws_size,
                              hipStream_t stream)
{
    const float* rois     = (const float*)d_in[0];
    const float* feat     = (const float*)d_in[1];
    const int*   stride_p = (const int*)d_in[2];
    float*       out      = (float*)d_out;

    dim3 grid(NBLK);   // persistent: 2 blocks/CU, each handles ch and ch+512
    dim3 block(512);
    hipLaunchKernelGGL(psroi_fused, grid, block, 0, stream, rois, feat, stride_p, out);
}